// Round 2
// baseline (64.561 us; speedup 1.0000x reference)
//
#include <hip/hip_runtime.h>
#include <stdint.h>

#define N_ATOMS 8192
#define KNB 32            // MAX_NEIGHBORS
#define CUTOFF_F 5.0f
#define N_MOLS 64
#define CAP 256           // max supported molecule size (Binomial(8192,1/64): P(>195) ~ 1e-7)
#define WPB 4             // atoms (waves) per 256-thread block
#define WIN 512           // batch scan window: covers >=CAP back and >=CAP fwd of block's atoms

// Single-wave LDS producer->consumer sync (lanes lockstep, DS pipe in-order
// per wave). asm clobber stops compiler reordering, lgkmcnt(0) drains DS,
// sched_barrier pins it (guide rule #18).
__device__ __forceinline__ void wave_lds_fence() {
    asm volatile("s_waitcnt lgkmcnt(0)" ::: "memory");
    __builtin_amdgcn_sched_barrier(0);
}

// One 64-lane wave per atom, 4 atoms per 256-thread block.
// Phase 0 (block-cooperative, latency-optimal): one coalesced int-pair load
//   per thread covers a 512-entry window of the sorted batch array around the
//   block's atoms; boundaries detected in LDS; per-wave (start,end) resolved
//   via a few shared atomics. Replaces 2-6 DEPENDENT global rounds per wave
//   with 1 independent round + 2 barriers. Also removes the per-wave batch[i]
//   load from the critical chain entirely.
// Phase 1: candidate loads pre-issued for all chunks in one memory round
//   (predicated unroll, no break-serialization), then ballot-compacted into
//   LDS as (dist_bits<<32 | j) keys.
// Phase 2: exact rank selection (#{strictly smaller} == slot) — identical to
//   jax.lax.top_k stable ascending order.
// Phase 3: coalesced 32-lane output write; pads are self-edges -> vec==0.
__global__ __launch_bounds__(64 * WPB) void radius_graph_fused(
    const float* __restrict__ pos, const int* __restrict__ batch,
    float* __restrict__ out)
{
    const int tid  = threadIdx.x;
    const int w    = tid >> 6;             // wave id within block
    const int lane = tid & 63;
    const int i0   = blockIdx.x * WPB;     // first atom of this block
    const int i    = i0 + w;               // atom handled by this wave

    __shared__ int      sb[WIN + 2];       // batch window [base-1 .. base+WIN]
    __shared__ int      s_start[WPB], s_end[WPB];
    __shared__ uint64_t list[WPB][CAP];
    __shared__ int      win_[WPB][KNB];

    // ---- Phase 0a: cooperative window load (one independent round) ----
    const int base = i0 - 256;             // window positions [base, base+511]
    {
        const int e0 = base + 2 * tid;
        const int e1 = e0 + 1;
        // sentinels: <0 -> -1, >=N -> -2 (distinct, both != any batch value)
        const int v0 = (e0 >= 0) ? ((e0 < N_ATOMS) ? batch[e0] : -2) : -1;
        const int v1 = (e1 >= 0) ? ((e1 < N_ATOMS) ? batch[e1] : -2) : -1;
        sb[2 * tid + 1] = v0;
        sb[2 * tid + 2] = v1;
        if (tid == 0) {
            const int em = base - 1;
            sb[0] = (em >= 0) ? batch[em] : -1;   // em < N always (base <= i0)
        }
        if (tid < WPB) { s_start[tid] = 0; s_end[tid] = N_ATOMS; }
    }
    __syncthreads();

    // ---- Phase 0b: boundary detect + per-wave range resolve ----
    // boundary at position p  <=>  B(p-1) != B(p); molecule(start..end) of
    // atom iw: start = max boundary <= iw, end = min boundary > iw. CAP
    // guarantees both fall inside the window.
    {
        #pragma unroll
        for (int z = 0; z < 2; ++z) {
            const int k = 2 * tid + z;         // p = base + k, k in [0,511]
            const int p = base + k;
            if (p >= 0 && p <= N_ATOMS && sb[k] != sb[k + 1]) {
                #pragma unroll
                for (int ww = 0; ww < WPB; ++ww) {
                    const int iw = i0 + ww;
                    if (p <= iw) atomicMax(&s_start[ww], p);
                    else         atomicMin(&s_end[ww], p);
                }
            }
        }
    }
    __syncthreads();
    const int start = s_start[w];
    const int end   = s_end[w];

    const float xi = pos[3 * i], yi = pos[3 * i + 1], zi = pos[3 * i + 2];
    const float sqi = xi * xi + yi * yi + zi * zi;

    // ---- Phase 1: all candidate loads in one round, then compaction ----
    const int len = end - start;
    int nq = (len + 63) >> 6;              // wave-uniform chunk count
    if (nq > 4) nq = 4;                    // CAP guard
    bool     valid[4];
    uint64_t key[4];
    #pragma unroll
    for (int q = 0; q < 4; ++q) {          // predicated: loads issue together
        valid[q] = false; key[q] = 0;
        const int j = start + (q << 6) + lane;
        if (q < nq && j < end && j != i) {
            const float xj = pos[3 * j], yj = pos[3 * j + 1], zj = pos[3 * j + 2];
            const float sqj = xj * xj + yj * yj + zj * zj;
            const float dot = xi * xj + yi * yj + zi * zj;
            const float d2  = (sqi + sqj) - 2.0f * dot;     // reference's gram trick
            const float dist = sqrtf(fmaxf(d2, 0.0f));
            if (dist <= CUTOFF_F) {
                valid[q] = true;
                key[q] = ((uint64_t)__float_as_uint(dist) << 32) | (uint32_t)j;
            }
        }
    }
    int cnt = 0;                           // wave-uniform valid count
    #pragma unroll
    for (int q = 0; q < 4; ++q) {
        if (q >= nq) break;                // uniform exit
        const unsigned long long m = __ballot(valid[q]);
        if (valid[q])
            list[w][cnt + __popcll(m & ((1ULL << lane) - 1ULL))] = key[q];
        cnt += __popcll(m);
    }

    if (lane < KNB) win_[w][lane] = i;     // default pad: self-edge
    wave_lds_fence();                      // list/win writes visible wave-wide

    // ---- Phase 2: exact rank selection ----
    const int C = cnt;
    for (int t = lane; t < C; t += 64) {
        const uint64_t my = list[w][t];
        int r = 0;
        #pragma unroll 4
        for (int u = 0; u < C; ++u) r += (list[w][u] < my) ? 1 : 0;  // broadcast reads
        if (r < KNB) win_[w][r] = (int)(uint32_t)(my & 0xFFFFFFFFu);
    }
    wave_lds_fence();                      // win writes visible before readback

    // ---- Phase 3: coalesced output write ----
    if (lane < KNB) {
        const int dst = win_[w][lane];
        const long long NK = (long long)N_ATOMS * KNB;
        const long long e  = (long long)i * KNB + lane;
        out[e]      = (float)i;
        out[NK + e] = (float)dst;
        // real edge: pos[dst]-pos[i]; pad: dst==i -> exactly 0.0
        out[2 * NK + 3 * e]     = pos[3 * dst]     - xi;
        out[2 * NK + 3 * e + 1] = pos[3 * dst + 1] - yi;
        out[2 * NK + 3 * e + 2] = pos[3 * dst + 2] - zi;
        out[5 * NK + e] = (lane < C) ? 1.0f : 0.0f;
    }
}

extern "C" void kernel_launch(void* const* d_in, const int* in_sizes, int n_in,
                              void* d_out, int out_size, void* d_ws, size_t ws_size,
                              hipStream_t stream) {
    const float* pos   = (const float*)d_in[0];   // [8192, 3] f32
    const int*   batch = (const int*)d_in[1];     // [8192] i32, sorted
    float*       out   = (float*)d_out;           // 6*N*K floats
    (void)d_ws; (void)ws_size;

    radius_graph_fused<<<N_ATOMS / WPB, 64 * WPB, 0, stream>>>(pos, batch, out);
}